// Round 2
// baseline (336.586 us; speedup 1.0000x reference)
//
#include <hip/hip_runtime.h>

typedef _Float16 half8  __attribute__((ext_vector_type(8)));
typedef _Float16 half4v __attribute__((ext_vector_type(4)));
typedef float    float4v __attribute__((ext_vector_type(4)));

#define N_ 4096
#define B_ 8
#define D_ 64
#define F_ 128

// ---------------- K1: pack adjacency to bitmask ----------------
__global__ __launch_bounds__(256) void pack_adj_kernel(const int* __restrict__ adj,
                                                       unsigned long long* __restrict__ bits) {
  int i = blockIdx.x * 256 + threadIdx.x;
  unsigned long long m = __ballot(adj[i] > 0);
  if ((threadIdx.x & 63) == 0) bits[i >> 6] = m;
}

// ---------------- K2: Wh = h @ W  (fp32 FMA -> fp16 store) ----------------
__global__ __launch_bounds__(256) void wh_kernel(const float* __restrict__ h,
                                                 const float* __restrict__ W,
                                                 _Float16* __restrict__ Wh16) {
  int row = blockIdx.x * 256 + threadIdx.x;
  const float* hr = h + (size_t)row * F_;
  _Float16* outr = Wh16 + (size_t)row * D_;
#pragma unroll 1
  for (int ob = 0; ob < 8; ++ob) {
    float acc[8] = {0.f,0.f,0.f,0.f,0.f,0.f,0.f,0.f};
    for (int f = 0; f < F_; ++f) {
      float hv = hr[f];
      const float* wf = W + f * D_ + ob * 8;   // wave-uniform -> s_load
#pragma unroll
      for (int o = 0; o < 8; ++o) acc[o] += hv * wf[o];
    }
    half8 r;
#pragma unroll
    for (int o = 0; o < 8; ++o) r[o] = (_Float16)acc[o];
    *(half8*)(outr + ob * 8) = r;
  }
}

// ---------------- K2b: WhT[b][d][n] = Wh[b][n][d] ----------------
__global__ __launch_bounds__(256) void tr_kernel(const _Float16* __restrict__ Wh16,
                                                 _Float16* __restrict__ WhT16) {
  __shared__ __align__(16) _Float16 tl[64][72];
  int bid = blockIdx.x;
  int b  = bid >> 6;
  int kb = (bid & 63) * 64;
  int t  = threadIdx.x;
  int kl = t >> 2, c0 = (t & 3) * 16;
  const _Float16* src = Wh16 + ((size_t)(b * N_ + kb + kl)) * D_ + c0;
  *(half8*)&tl[kl][c0]     = *(const half8*)src;
  *(half8*)&tl[kl][c0 + 8] = *(const half8*)(src + 8);
  __syncthreads();
  int dl = t >> 2, k0 = (t & 3) * 16;
  half8 o0, o1;
#pragma unroll
  for (int i = 0; i < 8; ++i) o0[i] = tl[k0 + i][dl];
#pragma unroll
  for (int i = 0; i < 8; ++i) o1[i] = tl[k0 + 8 + i][dl];
  _Float16* dst = WhT16 + ((size_t)(b * D_ + dl)) * N_ + kb + k0;
  *(half8*)dst       = o0;
  *(half8*)(dst + 8) = o1;
}

// ---------------- K3: flash attention + ELU ----------------
// grid: 8 batches * 32 q-chunks(128 rows); block: 256 thr = 4 independent waves,
// each wave owns 32 q-rows. Swapped QK^T: S^T = mfma(K, Q) -> lane's scores all
// belong to q = (lane&15). No __syncthreads anywhere (P LDS is wave-private).
__global__ __launch_bounds__(256, 1) void attn_kernel(
    const unsigned long long* __restrict__ bits,
    const _Float16* __restrict__ Wh,
    const _Float16* __restrict__ WhT,
    float* __restrict__ out) {
  __shared__ float4v p_smem[4][256];   // 4 KiB per wave, fragmented P layout
  const int tid  = threadIdx.x;
  const int w    = tid >> 6;
  const int lane = tid & 63;
  const int g    = lane >> 4;
  const int c    = lane & 15;
  const int bid  = blockIdx.x;
  const int b    = bid >> 5;
  const int q0   = (bid & 31) * 128 + w * 32;

  const _Float16* Whb  = Wh  + (size_t)b * N_ * D_;
  const _Float16* WhTb = WhT + (size_t)b * D_ * N_;
  char* pbase = (char*)&p_smem[w][0];

  // Q fragments, pre-scaled by 1/sqrt(64)=0.125 (exact in fp16)
  half8 qf[2][2];
#pragma unroll
  for (int qb = 0; qb < 2; ++qb)
#pragma unroll
    for (int ds = 0; ds < 2; ++ds) {
      half8 v = *(const half8*)(Whb + (size_t)(q0 + qb * 16 + c) * D_ + ds * 32 + g * 8);
      qf[qb][ds] = v * (_Float16)0.125f;
    }

  float4v o_acc[2][4];
#pragma unroll
  for (int rb = 0; rb < 2; ++rb)
#pragma unroll
    for (int dsub = 0; dsub < 4; ++dsub)
      o_acc[rb][dsub] = (float4v){0.f, 0.f, 0.f, 0.f};

  float mrow[2] = {-1e30f, -1e30f};
  float lrow[2] = {0.f, 0.f};

  const unsigned long long* bq0 = bits + (size_t)(q0 + c) * 64;
  const unsigned long long* bq1 = bits + (size_t)(q0 + 16 + c) * 64;

  for (int t = 0; t < N_ / 64; ++t) {
    const int k0 = t * 64;
    unsigned long long bw[2];
    bw[0] = bq0[t];
    bw[1] = bq1[t];

    // ---- S^T tile: rows = k (16 per subtile), cols = q ----
    float4v sac[4][2];
#pragma unroll
    for (int st = 0; st < 4; ++st) {
      const _Float16* kp = Whb + (size_t)(k0 + st * 16 + c) * D_ + g * 8;
      half8 kf0 = *(const half8*)(kp);
      half8 kf1 = *(const half8*)(kp + 32);
#pragma unroll
      for (int qb = 0; qb < 2; ++qb) {
        float4v z = (float4v){0.f, 0.f, 0.f, 0.f};
        z = __builtin_amdgcn_mfma_f32_16x16x32_f16(kf0, qf[qb][0], z, 0, 0, 0);
        z = __builtin_amdgcn_mfma_f32_16x16x32_f16(kf1, qf[qb][1], z, 0, 0, 0);
        sac[st][qb] = z;
      }
    }

    // ---- mask + tile max ----
    float tmax[2] = {-1e30f, -1e30f};
#pragma unroll
    for (int st = 0; st < 4; ++st)
#pragma unroll
      for (int qb = 0; qb < 2; ++qb) {
        unsigned wbits = (unsigned)(bw[qb] >> (st * 16 + g * 4));
#pragma unroll
        for (int j = 0; j < 4; ++j) {
          float v = (wbits & (1u << j)) ? sac[st][qb][j] : -1e9f;
          sac[st][qb][j] = v;
          tmax[qb] = fmaxf(tmax[qb], v);
        }
      }
#pragma unroll
    for (int qb = 0; qb < 2; ++qb) {
      tmax[qb] = fmaxf(tmax[qb], __shfl_xor(tmax[qb], 16));
      tmax[qb] = fmaxf(tmax[qb], __shfl_xor(tmax[qb], 32));
    }

    float alpha[2], psum[2];
#pragma unroll
    for (int qb = 0; qb < 2; ++qb) {
      float mnew = fmaxf(mrow[qb], tmax[qb]);
      alpha[qb] = __expf(mrow[qb] - mnew);
      mrow[qb]  = mnew;
      psum[qb]  = 0.f;
    }

    // ---- P = exp(v - m), row sums ----
#pragma unroll
    for (int st = 0; st < 4; ++st)
#pragma unroll
      for (int qb = 0; qb < 2; ++qb)
#pragma unroll
        for (int j = 0; j < 4; ++j) {
          float p = __expf(sac[st][qb][j] - mrow[qb]);
          sac[st][qb][j] = p;
          psum[qb] += p;
        }
#pragma unroll
    for (int qb = 0; qb < 2; ++qb) {
      psum[qb] += __shfl_xor(psum[qb], 16);
      psum[qb] += __shfl_xor(psum[qb], 32);
      lrow[qb] = lrow[qb] * alpha[qb] + psum[qb];
    }

    // ---- rescale O by alpha (alpha lives at lane with c == q-local) ----
#pragma unroll
    for (int rb = 0; rb < 2; ++rb)
#pragma unroll
      for (int j = 0; j < 4; ++j) {
        float aj = __shfl(alpha[rb], (lane & 48) | (g * 4 + j));
#pragma unroll
        for (int dsub = 0; dsub < 4; ++dsub)
          o_acc[rb][dsub][j] *= aj;
      }

    // ---- write P to wave-private LDS (fragmented, conflict-free) ----
#pragma unroll
    for (int st = 0; st < 4; ++st)
#pragma unroll
      for (int qb = 0; qb < 2; ++qb) {
        half4v ph;
#pragma unroll
        for (int j = 0; j < 4; ++j) ph[j] = (_Float16)sac[st][qb][j];
        int off = ((qb * 8 + st * 2 + (g >> 1)) * 16 + c) * 16 + (g & 1) * 8;
        *(half4v*)(pbase + off) = ph;
      }

    // ---- PV: O += P * V ----
#pragma unroll
    for (int ks = 0; ks < 2; ++ks) {
      half8 af[2];
#pragma unroll
      for (int rb = 0; rb < 2; ++rb)
        af[rb] = *(const half8*)(pbase + ((rb * 8 + ks * 4 + g) * 16 + c) * 16);
#pragma unroll
      for (int dsub = 0; dsub < 4; ++dsub) {
        half8 vf = *(const half8*)(WhTb + (size_t)(dsub * 16 + c) * N_ + k0 + ks * 32 + g * 8);
#pragma unroll
        for (int rb = 0; rb < 2; ++rb)
          o_acc[rb][dsub] = __builtin_amdgcn_mfma_f32_16x16x32_f16(af[rb], vf, o_acc[rb][dsub], 0, 0, 0);
      }
    }
  }

  // ---- epilogue: O/l, ELU, store ----
#pragma unroll
  for (int rb = 0; rb < 2; ++rb) {
    float inv = 1.0f / lrow[rb];
#pragma unroll
    for (int j = 0; j < 4; ++j) {
      float li = __shfl(inv, (lane & 48) | (g * 4 + j));
      const int qg = q0 + rb * 16 + g * 4 + j;
#pragma unroll
      for (int dsub = 0; dsub < 4; ++dsub) {
        float x = o_acc[rb][dsub][j] * li;
        x = x > 0.f ? x : (__expf(x) - 1.0f);
        out[((size_t)b * N_ + qg) * D_ + dsub * 16 + c] = x;
      }
    }
  }
}

extern "C" void kernel_launch(void* const* d_in, const int* in_sizes, int n_in,
                              void* d_out, int out_size, void* d_ws, size_t ws_size,
                              hipStream_t stream) {
  const float* h = (const float*)d_in[0];
  const float* W = (const float*)d_in[1];
  const int* adj = (const int*)d_in[2];
  float* out = (float*)d_out;

  char* ws = (char*)d_ws;
  unsigned long long* bits = (unsigned long long*)ws;      // 2 MiB
  _Float16* Wh16  = (_Float16*)(ws + (2u << 20));          // 4 MiB
  _Float16* WhT16 = (_Float16*)(ws + (6u << 20));          // 4 MiB

  hipLaunchKernelGGL(pack_adj_kernel, dim3((N_ * N_) / 256), dim3(256), 0, stream, adj, bits);
  hipLaunchKernelGGL(wh_kernel,   dim3((B_ * N_) / 256), dim3(256), 0, stream, h, W, Wh16);
  hipLaunchKernelGGL(tr_kernel,   dim3(B_ * (N_ / 64)), dim3(256), 0, stream, Wh16, WhT16);
  hipLaunchKernelGGL(attn_kernel, dim3(B_ * (N_ / 128)), dim3(256), 0, stream, bits, Wh16, WhT16, out);
}

// Round 5
// 212.328 us; speedup vs baseline: 1.5852x; 1.5852x over previous
//
#include <hip/hip_runtime.h>

typedef _Float16 half8  __attribute__((ext_vector_type(8)));
typedef _Float16 half4v __attribute__((ext_vector_type(4)));
typedef float    float4v __attribute__((ext_vector_type(4)));

#define N_ 4096
#define B_ 8
#define D_ 64
#define F_ 128

// ---------------- K1: pack adjacency to bitmask ----------------
__global__ __launch_bounds__(256) void pack_adj_kernel(const int* __restrict__ adj,
                                                       unsigned long long* __restrict__ bits) {
  int i = blockIdx.x * 256 + threadIdx.x;
  unsigned long long m = __ballot(adj[i] > 0);
  if ((threadIdx.x & 63) == 0) bits[i >> 6] = m;
}

// ---------------- K2: Wh = h @ W (LDS-tiled, fp32 acc -> fp16) ----------------
__global__ __launch_bounds__(256) void wh_kernel(const float* __restrict__ h,
                                                 const float* __restrict__ W,
                                                 _Float16* __restrict__ Wh16) {
  __shared__ __align__(16) float    hs[64][132];   // h tile, 64 rows x 128 (pad 132, 16B-aligned rows)
  __shared__ __align__(16) _Float16 wt[64][132];   // W^T in fp16: wt[c][f]
  const int t = threadIdx.x;
  const int rowbase = blockIdx.x * 64;
  const float4v* hg = (const float4v*)(h + (size_t)rowbase * F_);
#pragma unroll
  for (int k = 0; k < 8; ++k) {
    int i4 = t + k * 256;
    float4v v = hg[i4];
    int r = i4 >> 5, c4 = (i4 & 31) * 4;
    *(float4v*)&hs[r][c4] = v;
  }
#pragma unroll
  for (int k = 0; k < 8; ++k) {
    int i4 = t + k * 256;
    float4v v = ((const float4v*)W)[i4];
    int f = i4 >> 4, c4 = (i4 & 15) * 4;
    wt[c4 + 0][f] = (_Float16)v[0];
    wt[c4 + 1][f] = (_Float16)v[1];
    wt[c4 + 2][f] = (_Float16)v[2];
    wt[c4 + 3][f] = (_Float16)v[3];
  }
  __syncthreads();
  const int w = t >> 6, lane = t & 63;
  const int r0 = w * 16;
  float acc[16];
#pragma unroll
  for (int i = 0; i < 16; ++i) acc[i] = 0.f;
#pragma unroll 4
  for (int f4 = 0; f4 < 32; ++f4) {
    half4v wv = *(half4v*)&wt[lane][f4 * 4];       // (lane*132+f4*4)*2 : 8B-aligned
    float w0 = (float)wv[0], w1 = (float)wv[1], w2 = (float)wv[2], w3 = (float)wv[3];
#pragma unroll
    for (int i = 0; i < 16; ++i) {
      float4v hv = *(float4v*)&hs[r0 + i][f4 * 4]; // broadcast read (uniform addr in wave)
      acc[i] += hv[0] * w0 + hv[1] * w1 + hv[2] * w2 + hv[3] * w3;
    }
  }
#pragma unroll
  for (int i = 0; i < 16; ++i)
    Wh16[(size_t)(rowbase + r0 + i) * D_ + lane] = (_Float16)acc[i];
}

// ---------------- K2b: WhT[b][d][n] = Wh[b][n][d] ----------------
__global__ __launch_bounds__(256) void tr_kernel(const _Float16* __restrict__ Wh16,
                                                 _Float16* __restrict__ WhT16) {
  __shared__ __align__(16) _Float16 tl[64][72];
  int bid = blockIdx.x;
  int b  = bid >> 6;
  int kb = (bid & 63) * 64;
  int t  = threadIdx.x;
  int kl = t >> 2, c0 = (t & 3) * 16;
  const _Float16* src = Wh16 + ((size_t)(b * N_ + kb + kl)) * D_ + c0;
  *(half8*)&tl[kl][c0]     = *(const half8*)src;
  *(half8*)&tl[kl][c0 + 8] = *(const half8*)(src + 8);
  __syncthreads();
  int dl = t >> 2, k0 = (t & 3) * 16;
  half8 o0, o1;
#pragma unroll
  for (int i = 0; i < 8; ++i) o0[i] = tl[k0 + i][dl];
#pragma unroll
  for (int i = 0; i < 8; ++i) o1[i] = tl[k0 + 8 + i][dl];
  _Float16* dst = WhT16 + ((size_t)(b * D_ + dl)) * N_ + kb + k0;
  *(half8*)dst       = o0;
  *(half8*)(dst + 8) = o1;
}

// ---------------- K3: flash attention + ELU ----------------
// Block = 512 thr = 8 waves: 4 q-chunks (16 rows) x 2 KV-halves (in-block split-K).
// K/V tiles LDS-staged with XOR swizzle (slot ^= row&7), prefetch 1 tile ahead.
// Swapped QK^T: lane's 16 scores belong to q = lane&15. Mask BEFORE max
// (fp16 P storage requires P_max = 1; deferred masking underflows fp16).
// Epilogue merges the two KV-half partials (m,l,O) via LDS.
__global__ __launch_bounds__(512, 4) void attn_kernel(
    const unsigned long long* __restrict__ bits,
    const _Float16* __restrict__ Wh,
    const _Float16* __restrict__ WhT,
    float* __restrict__ out) {
  __shared__ __align__(16) char lds[49152];        // [0,16K) Kst[2] | [16K,32K) Vst[2] | [32K,48K) P[8]
  const int tid  = threadIdx.x;
  const int w    = tid >> 6;
  const int lane = tid & 63;
  const int g    = lane >> 4;
  const int c    = lane & 15;
  const int qi   = w & 3;
  const int s    = w >> 2;
  const int bid  = blockIdx.x;
  const int b    = bid >> 6;
  const int q0b  = (bid & 63) * 64;
  const int q0w  = q0b + qi * 16;

  const _Float16* Whb  = Wh  + (size_t)b * N_ * D_;
  const _Float16* WhTb = WhT + (size_t)b * D_ * N_;
  _Float16* Kst = (_Float16*)(lds + s * 8192);
  _Float16* Vst = (_Float16*)(lds + 16384 + s * 8192);
  char* Pb = lds + 32768 + w * 2048;

  // staging map: e = (qi*2+i)*64 + lane ; row=e>>3, slot'=e&7, src slot = slot'^(row&7)
  const int e0  = (qi * 2 + 0) * 64 + lane;
  const int e1  = (qi * 2 + 1) * 64 + lane;
  const int r0e = e0 >> 3, s0e = (e0 & 7) ^ (r0e & 7);
  const int r1e = e1 >> 3, s1e = (e1 & 7) ^ (r1e & 7);

  half8 qf[2];
#pragma unroll
  for (int ds = 0; ds < 2; ++ds) {
    half8 v = *(const half8*)(Whb + (size_t)(q0w + c) * D_ + ds * 32 + g * 8);
    qf[ds] = v * (_Float16)0.125f;            // fold 1/sqrt(64)
  }

  float4v o_acc[4];
#pragma unroll
  for (int d = 0; d < 4; ++d) o_acc[d] = (float4v){0.f, 0.f, 0.f, 0.f};
  float mrow = -1e30f, lrow = 0.f;

  const unsigned long long* bq = bits + (size_t)(q0w + c) * 64 + s * 32;

  // prefetch tile 0
  int k0n = (s * 32) * 64;
  half8 ka = *(const half8*)(Whb + (size_t)(k0n + r0e) * D_ + s0e * 8);
  half8 kb = *(const half8*)(Whb + (size_t)(k0n + r1e) * D_ + s1e * 8);
  half8 va = *(const half8*)(WhTb + (size_t)r0e * N_ + k0n + s0e * 8);
  half8 vb = *(const half8*)(WhTb + (size_t)r1e * N_ + k0n + s1e * 8);
  unsigned long long bw = bq[0];

  for (int t = 0; t < 32; ++t) {
    __syncthreads();                               // previous tile's LDS reads done
    *(half8*)(Kst + e0 * 8) = ka;
    *(half8*)(Kst + e1 * 8) = kb;
    *(half8*)(Vst + e0 * 8) = va;
    *(half8*)(Vst + e1 * 8) = vb;
    __syncthreads();                               // stage visible

    const int t1 = (t + 1 < 32) ? t + 1 : 31;      // uniform; last iter redundant
    k0n = (s * 32 + t1) * 64;
    ka = *(const half8*)(Whb + (size_t)(k0n + r0e) * D_ + s0e * 8);
    kb = *(const half8*)(Whb + (size_t)(k0n + r1e) * D_ + s1e * 8);
    va = *(const half8*)(WhTb + (size_t)r0e * N_ + k0n + s0e * 8);
    vb = *(const half8*)(WhTb + (size_t)r1e * N_ + k0n + s1e * 8);
    unsigned long long bwn = bq[t1];

    // ---- QK^T (S^T tile: rows=k, cols=q) ----
    float4v sac[4];
#pragma unroll
    for (int st = 0; st < 4; ++st) {
      const _Float16* kr = Kst + (st * 16 + c) * 64;
      half8 kf0 = *(const half8*)(kr + ((g       ^ (c & 7)) * 8));
      half8 kf1 = *(const half8*)(kr + (((g + 4) ^ (c & 7)) * 8));
      float4v z = (float4v){0.f, 0.f, 0.f, 0.f};
      z = __builtin_amdgcn_mfma_f32_16x16x32_f16(kf0, qf[0], z, 0, 0, 0);
      z = __builtin_amdgcn_mfma_f32_16x16x32_f16(kf1, qf[1], z, 0, 0, 0);
      sac[st] = z;
    }

    // ---- mask to -1e9 BEFORE max (keeps P_max = 1 for fp16 storage) ----
    float tmax = -1e30f;
#pragma unroll
    for (int st = 0; st < 4; ++st) {
      unsigned wb = (unsigned)(bw >> (st * 16 + g * 4));
#pragma unroll
      for (int j = 0; j < 4; ++j) {
        float v = (wb & (1u << j)) ? sac[st][j] : -1e9f;
        sac[st][j] = v;
        tmax = fmaxf(tmax, v);
      }
    }
    tmax = fmaxf(tmax, __shfl_xor(tmax, 16));
    tmax = fmaxf(tmax, __shfl_xor(tmax, 32));

    float mnew  = fmaxf(mrow, tmax);
    float alpha = __expf(mrow - mnew);             // first tile: exp(-inf)=0
    mrow = mnew;
    lrow *= alpha;
#pragma unroll
    for (int j = 0; j < 4; ++j) {
      float aj = __shfl(alpha, (lane & 48) | (g * 4 + j));
#pragma unroll
      for (int d = 0; d < 4; ++d) o_acc[d][j] *= aj;
    }

    // ---- P = exp(s-m) (masked entries: exp(-1e9-m) = 0), pack fp16, LDS ----
#pragma unroll
    for (int st = 0; st < 4; ++st) {
      float p0 = __expf(sac[st][0] - mrow);
      float p1 = __expf(sac[st][1] - mrow);
      float p2 = __expf(sac[st][2] - mrow);
      float p3 = __expf(sac[st][3] - mrow);
      lrow += (p0 + p1) + (p2 + p3);
      uint2 pr;
      pr.x = __builtin_bit_cast(unsigned, __builtin_amdgcn_cvt_pkrtz(p0, p1));
      pr.y = __builtin_bit_cast(unsigned, __builtin_amdgcn_cvt_pkrtz(p2, p3));
      const int cell = st * 2 + (g >> 1);
      *(uint2*)(Pb + (cell * 16 + c) * 16 + (g & 1) * 8) = pr;
    }

    // ---- PV: O += P * V ----
#pragma unroll
    for (int ks = 0; ks < 2; ++ks) {
      half8 af = *(const half8*)(Pb + ((ks * 4 + g) * 16 + c) * 16);
#pragma unroll
      for (int d = 0; d < 4; ++d) {
        const int vrow = d * 16 + c;
        half8 vf = *(const half8*)(Vst + vrow * 64 + (((ks * 4 + g) ^ (c & 7)) * 8));
        o_acc[d] = __builtin_amdgcn_mfma_f32_16x16x32_f16(af, vf, o_acc[d], 0, 0, 0);
      }
    }
    bw = bwn;
  }

  // ---- epilogue: reduce l, merge the two KV-half partials, ELU, store ----
  lrow += __shfl_xor(lrow, 16);
  lrow += __shfl_xor(lrow, 32);
  __syncthreads();                                 // all LDS (stage+P) dead; reuse for merge
  float* Ob = (float*)lds;                         // [128][66] fp32
#pragma unroll
  for (int d = 0; d < 4; ++d)
#pragma unroll
    for (int j = 0; j < 4; ++j)
      Ob[(w * 16 + g * 4 + j) * 66 + d * 16 + c] = o_acc[d][j];
  float2* mlb = (float2*)(lds + 36864);
  if (g == 0) mlb[w * 16 + c] = make_float2(mrow, lrow);
  __syncthreads();

#pragma unroll
  for (int it = 0; it < 8; ++it) {
    int r   = w + it * 8;                          // 0..63
    int col = lane;
    int qq = r >> 4, rl = r & 15;
    float2 ml0 = mlb[qq * 16 + rl];                // s=0 partial (wave qq)
    float2 ml1 = mlb[(qq + 4) * 16 + rl];          // s=1 partial (wave qq+4)
    float mm = fmaxf(ml0.x, ml1.x);
    float a0 = __expf(ml0.x - mm);
    float a1 = __expf(ml1.x - mm);
    float l  = a0 * ml0.y + a1 * ml1.y;
    float o  = a0 * Ob[(qq * 16 + rl) * 66 + col] + a1 * Ob[((qq + 4) * 16 + rl) * 66 + col];
    float x  = o / l;
    x = x > 0.f ? x : (__expf(x) - 1.f);
    out[((size_t)b * N_ + q0b + r) * D_ + col] = x;
  }
}

extern "C" void kernel_launch(void* const* d_in, const int* in_sizes, int n_in,
                              void* d_out, int out_size, void* d_ws, size_t ws_size,
                              hipStream_t stream) {
  const float* h = (const float*)d_in[0];
  const float* W = (const float*)d_in[1];
  const int* adj = (const int*)d_in[2];
  float* out = (float*)d_out;

  char* ws = (char*)d_ws;
  unsigned long long* bits = (unsigned long long*)ws;      // 2 MiB
  _Float16* Wh16  = (_Float16*)(ws + (2u << 20));          // 4 MiB
  _Float16* WhT16 = (_Float16*)(ws + (6u << 20));          // 4 MiB

  hipLaunchKernelGGL(pack_adj_kernel, dim3((N_ * N_) / 256), dim3(256), 0, stream, adj, bits);
  hipLaunchKernelGGL(wh_kernel,   dim3((B_ * N_) / 64), dim3(256), 0, stream, h, W, Wh16);
  hipLaunchKernelGGL(tr_kernel,   dim3(B_ * (N_ / 64)), dim3(256), 0, stream, Wh16, WhT16);
  hipLaunchKernelGGL(attn_kernel, dim3(B_ * (N_ / 64)), dim3(512), 0, stream, bits, Wh16, WhT16, out);
}